// Round 15
// baseline (444.699 us; speedup 1.0000x reference)
//
#include <hip/hip_runtime.h>
#include <math.h>

typedef __bf16 bf16x8 __attribute__((ext_vector_type(8)));
typedef float f32x4 __attribute__((ext_vector_type(4)));
typedef unsigned short u16;
typedef unsigned int u32;

#define T_SEQ 2048
#define NHEAD 32

// float -> bf16 bits, round-nearest-even
__device__ __forceinline__ u16 f2bu(float f){
  u32 u = __float_as_uint(f);
  u32 r = (u + 0x7fffu + ((u >> 16) & 1u)) >> 16;
  return (u16)r;
}

__device__ __forceinline__ void gload_lds16(const void* g, void* l){
  __builtin_amdgcn_global_load_lds((const __attribute__((address_space(1))) u32*)g,
                                   (__attribute__((address_space(3))) u32*)l, 16, 0, 0);
}

// ---------------- transpose + cast body (vectorized) ----------------
__device__ __forceinline__ void tc_body(const float* __restrict__ src, u16* __restrict__ dst,
                                        int K, int N, int k0, int n0){
  __shared__ float tile[64][65];
  int t = threadIdx.x;
  int rr = t >> 4, c4 = (t & 15) * 4;
  #pragma unroll
  for (int i = 0; i < 4; i++){
    int r = rr + i * 16;
    int n = n0 + c4;
    float4 v;
    if (n < N) v = *(const float4*)(src + (size_t)(k0 + r) * N + n);
    else       v = make_float4(0.f, 0.f, 0.f, 0.f);
    tile[r][c4]     = v.x;
    tile[r][c4 + 1] = v.y;
    tile[r][c4 + 2] = v.z;
    tile[r][c4 + 3] = v.w;
  }
  __syncthreads();
  #pragma unroll
  for (int i = 0; i < 4; i++){
    int n = rr + i * 16;
    ushort4 o;
    o.x = f2bu(tile[c4 + 0][n]);
    o.y = f2bu(tile[c4 + 1][n]);
    o.z = f2bu(tile[c4 + 2][n]);
    o.w = f2bu(tile[c4 + 3][n]);
    *(ushort4*)(dst + (size_t)(n0 + n) * K + k0 + c4) = o;
  }
}

// ---------------- pre_batch: 5 weight transposes + hidden cast + rope table ----------------
// blocks: [0,9600) transposes | [9600,11648) hidden cast | [11648,11904) rope table
__global__ __launch_bounds__(256) void pre_batch(
    const float* __restrict__ Wqa, u16* __restrict__ WqaT,
    const float* __restrict__ Wkva, u16* __restrict__ WkvaT,
    const float* __restrict__ Wqb, u16* __restrict__ WqbT,
    const float* __restrict__ Wkvb, u16* __restrict__ WkvbT,
    const float* __restrict__ Wo, u16* __restrict__ WoT,
    const float* __restrict__ hidden, u16* __restrict__ hidB,
    const int* __restrict__ positions, float* __restrict__ cosT,
    float* __restrict__ sinT, float lo, float denom){
  int bid = blockIdx.x;
  if (bid < 9600){
    const float* s; u16* d; int K, N, gx, l;
    if (bid < 1536)      { s = Wqa;  d = WqaT;  K = 4096; N = 1536; gx = 64; l = bid; }
    else if (bid < 2176) { s = Wkva; d = WkvaT; K = 4096; N = 576;  gx = 64; l = bid - 1536; }
    else if (bid < 4480) { s = Wqb;  d = WqbT;  K = 1536; N = 6144; gx = 24; l = bid - 2176; }
    else if (bid < 5504) { s = Wkvb; d = WkvbT; K = 512;  N = 8192; gx = 8;  l = bid - 4480; }
    else                 { s = Wo;   d = WoT;   K = 4096; N = 4096; gx = 64; l = bid - 5504; }
    tc_body(s, d, K, N, (l % gx) * 64, (l / gx) * 64);
  } else if (bid < 11648){
    int l = bid - 9600;
    #pragma unroll
    for (int i = 0; i < 4; i++){
      int idx = l * 1024 + threadIdx.x + i * 256;
      float4 v = ((const float4*)hidden)[idx];
      ushort4 o;
      o.x = f2bu(v.x); o.y = f2bu(v.y); o.z = f2bu(v.z); o.w = f2bu(v.w);
      ((ushort4*)hidB)[idx] = o;
    }
  } else {
    int idx = (bid - 11648) * 256 + threadIdx.x;
    int t = idx >> 5, i = idx & 31;
    float pf = powf(10000.f, (float)i / 32.f);
    float inv_extra = 1.f / pf;
    float inv_inter = 1.f / (40.f * pf);
    float ramp = fminf(fmaxf(((float)i - lo) / denom, 0.f), 1.f);
    float invf = inv_inter * ramp + inv_extra * (1.f - ramp);
    float fr = (float)positions[t] * invf;
    cosT[idx] = cosf(fr);
    sinT[idx] = sinf(fr);
  }
}

// ---------------- rmsnorm (f32 in, bf16 out) ----------------
__global__ void rmsnorm_cast(const float* __restrict__ in, int istride, int n,
                             const float* __restrict__ w, u16* __restrict__ out, int ostride){
  int row = blockIdx.x;
  const float* x = in + (size_t)row * istride;
  float ss = 0.f;
  for (int c = threadIdx.x; c < n; c += blockDim.x){ float v = x[c]; ss += v * v; }
  #pragma unroll
  for (int off = 1; off < 64; off <<= 1) ss += __shfl_xor(ss, off);
  __shared__ float wsum[4];
  if ((threadIdx.x & 63) == 0) wsum[threadIdx.x >> 6] = ss;
  __syncthreads();
  float tot = wsum[0] + wsum[1] + wsum[2] + wsum[3];
  float scale = rsqrtf(tot / (float)n + 1e-6f);
  for (int c = threadIdx.x; c < n; c += blockDim.x)
    out[(size_t)row * ostride + c] = f2bu(x[c] * scale * w[c]);
}

// ---------------- rope on k_pe ----------------
__global__ void rope_kpe(const float* __restrict__ lat, int lstride, int loff,
                         const float* __restrict__ cosT,
                         const float* __restrict__ sinT, u16* __restrict__ kpe){
  int idx = blockIdx.x * blockDim.x + threadIdx.x;
  if (idx >= T_SEQ * 32) return;
  int t = idx >> 5, i = idx & 31;
  float x1 = lat[(size_t)t * lstride + loff + 2 * i];
  float x2 = lat[(size_t)t * lstride + loff + 2 * i + 1];
  float c = cosT[idx], s = sinT[idx];
  kpe[t * 64 + 2 * i]     = f2bu(x1 * c - x2 * s);
  kpe[t * 64 + 2 * i + 1] = f2bu(x2 * c + x1 * s);
}

// ---------------- GEMM (round-4 structure) ----------------
// EPI 0: C f32 (M,N,K runtime; 2D grid).
// EPI 3: MERGED mid GEMMs, 1D grid of 1792 blocks:
//   seg0 (wg<768):  Qp = rope(qln @ WqbT)*scaling   (bn over 48, K=1536)
//   seg1 (wg>=768): Kp + Vt = kva @ WkvbT           (bn over 64, K=512)
template<int EPI>
__global__ __launch_bounds__(256) void gemm_bt(const u16* __restrict__ A, const u16* __restrict__ BT,
                                               float* __restrict__ C,
                                               u16* __restrict__ O1, u16* __restrict__ O2,
                                               u16* __restrict__ O3,
                                               const u16* __restrict__ A2, const u16* __restrict__ BT2,
                                               const float* __restrict__ cosT,
                                               const float* __restrict__ sinT,
                                               float scaling, int M, int N, int K){
  __shared__ __align__(1024) char lds[32768];
  const int tid = threadIdx.x;
  const int wave = tid >> 6, lane = tid & 63;
  const int lg = lane >> 4, lm = lane & 15;

  // bijective XCD swizzle (m204)
  int gx = gridDim.x;
  int nwg = gx * gridDim.y;
  int orig = blockIdx.y * gx + blockIdx.x;
  int qq = nwg >> 3, rr_ = nwg & 7, xc = orig & 7, rest = orig >> 3;
  int wg = (xc < rr_ ? xc * (qq + 1) : rr_ * (qq + 1) + (xc - rr_) * qq) + rest;

  const u16* Ap; const u16* BTp; int Kv, bn, bm, seg = 0;
  if constexpr (EPI == 3){
    if (wg < 768){ seg = 0; Ap = A;  BTp = BT;  Kv = 1536; bn = (wg % 48) * 128; bm = (wg / 48) * 128; }
    else         { seg = 1; Ap = A2; BTp = BT2; Kv = 512;  int l2 = wg - 768; bn = (l2 & 63) * 128; bm = (l2 >> 6) * 128; }
  } else {
    Ap = A; BTp = BT; Kv = K;
    bn = (wg % gx) * 128; bm = (wg / gx) * 128;
  }

  const int wr = (wave >> 1) * 64, wc = (wave & 1) * 64;
  f32x4 acc[4][4] = {};
  int srow[2], scol[2], soff[2];
  #pragma unroll
  for (int j = 0; j < 2; j++){
    int o = (wave * 2 + j) * 1024 + lane * 16;
    int row = o >> 6;
    int cg = ((o >> 4) & 3) ^ ((row >> 1) & 3);
    srow[j] = row; scol[j] = cg * 8; soff[j] = (wave * 2 + j) * 1024;
  }

  #pragma unroll
  for (int j = 0; j < 2; j++){
    gload_lds16(Ap  + (size_t)(bm + srow[j]) * Kv + scol[j], lds + soff[j]);
    gload_lds16(BTp + (size_t)(bn + srow[j]) * Kv + scol[j], lds + 16384 + soff[j]);
  }

  int cur = 0;
  for (int k0 = 0; k0 < Kv; k0 += 32){
    if (k0 + 32 < Kv){
      char* dA = lds + (cur ^ 1) * 8192;
      char* dB = lds + 16384 + (cur ^ 1) * 8192;
      #pragma unroll
      for (int j = 0; j < 2; j++){
        gload_lds16(Ap  + (size_t)(bm + srow[j]) * Kv + k0 + 32 + scol[j], dA + soff[j]);
        gload_lds16(BTp + (size_t)(bn + srow[j]) * Kv + k0 + 32 + scol[j], dB + soff[j]);
      }
      asm volatile("s_waitcnt vmcnt(4)" ::: "memory");
    } else {
      asm volatile("s_waitcnt vmcnt(0)" ::: "memory");
    }
    __builtin_amdgcn_sched_barrier(0);
    __builtin_amdgcn_s_barrier();

    const char* ldsA = lds + cur * 8192;
    const char* ldsB = lds + 16384 + cur * 8192;
    bf16x8 af[4], bfr[4];
    #pragma unroll
    for (int m = 0; m < 4; m++){
      int r = wr + m * 16 + lm;
      af[m] = *(const bf16x8*)(ldsA + r * 64 + ((lg ^ ((r >> 1) & 3)) << 4));
    }
    #pragma unroll
    for (int n = 0; n < 4; n++){
      int r = wc + n * 16 + lm;
      bfr[n] = *(const bf16x8*)(ldsB + r * 64 + ((lg ^ ((r >> 1) & 3)) << 4));
    }
    __builtin_amdgcn_s_setprio(1);
    #pragma unroll
    for (int m = 0; m < 4; m++)
      #pragma unroll
      for (int n = 0; n < 4; n++)
        acc[m][n] = __builtin_amdgcn_mfma_f32_16x16x32_bf16(af[m], bfr[n], acc[m][n], 0, 0, 0);
    __builtin_amdgcn_s_setprio(0);
    __builtin_amdgcn_s_barrier();
    cur ^= 1;
  }

  #pragma unroll
  for (int m = 0; m < 4; m++)
    #pragma unroll
    for (int n = 0; n < 4; n++){
      const int r0 = bm + wr + m * 16 + lg * 4;
      const int c  = bn + wc + n * 16 + lm;
      if (EPI == 0){
        #pragma unroll
        for (int q = 0; q < 4; q++)
          C[(size_t)(r0 + q) * N + c] = acc[m][n][q];
      } else {
        if (seg == 0){
          // Qp: fused RoPE + scaling
          #pragma unroll
          for (int q = 0; q < 4; q++){
            float v = acc[m][n][q];
            float vp = __shfl_xor(v, 1);
            int h = c / 192, d = c - h * 192;
            float outv;
            if (d < 128) outv = v;
            else {
              int i = (d - 128) >> 1;
              float co = cosT[(r0 + q) * 32 + i], si = sinT[(r0 + q) * 32 + i];
              outv = (d & 1) ? (v * co + vp * si) : (v * co - vp * si);
            }
            O1[(size_t)h * T_SEQ * 192 + (size_t)(r0 + q) * 192 + d] = f2bu(outv * scaling);
          }
        } else {
          int h = c >> 8, d = c & 255;
          if (d < 128){
            #pragma unroll
            for (int q = 0; q < 4; q++)
              O2[(size_t)h * T_SEQ * 128 + (size_t)(r0 + q) * 128 + d] = f2bu(acc[m][n][q]);
          } else {
            ushort4 o;
            o.x = f2bu(acc[m][n][0]); o.y = f2bu(acc[m][n][1]);
            o.z = f2bu(acc[m][n][2]); o.w = f2bu(acc[m][n][3]);
            *(ushort4*)(O3 + (size_t)(h * 128 + (d - 128)) * T_SEQ + r0) = o;
          }
        }
      }
    }
}

// ---------------- flash attention v12 (r14, unchanged) ----------------
__global__ __launch_bounds__(512, 4) void flash_attn(const u16* __restrict__ Qp, const u16* __restrict__ Kp,
                                                     const u16* __restrict__ kpe, const u16* __restrict__ Vt,
                                                     u16* __restrict__ attnb){
  const int b = blockIdx.x;
  const int h = (b & 7) + 8 * ((b >> 3) & 3);
  const int qt = (b < 256) ? (15 - (b >> 5)) : ((b - 256) >> 5);
  const int tid = threadIdx.x;
  const int wave = tid >> 6, lane = tid & 63;
  const int lg = lane >> 4, lm = lane & 15;
  const int qbase = qt * 128 + wave * 16;

  __shared__ __align__(1024) char lds[51200];
  u16* Pw = (u16*)(lds + 40960 + wave * 1280);   // [16][40] u16

  const u16* KpH = Kp + (size_t)h * T_SEQ * 128;
  const u16* VtH = Vt + (size_t)h * 128 * T_SEQ;

  int kO[2], kLoc[2], kPE[2];
  #pragma unroll
  for (int j = 0; j < 2; j++){
    int o = tid + 512 * j;
    int r = (o / 24) & 31, c = o % 24;
    int cx = c ^ (r & 7);
    kO[j] = o * 16;
    if (cx < 16){ kPE[j] = 0; kLoc[j] = r * 128 + cx * 8; }
    else        { kPE[j] = 1; kLoc[j] = r * 64 + (cx - 16) * 8; }
  }
  int vO, vSrc;
  { int o = tid; int d = o >> 2, c = o & 3; vO = o * 16; vSrc = d * T_SEQ + ((c ^ ((d >> 1) & 3)) << 3); }

  #define STAGE_KV(t, bi)                                                              \
    do {                                                                               \
      char* _k = lds + (bi) * 12288;                                                   \
      char* _v = lds + 24576 + (bi) * 8192;                                            \
      { const u16* _s = kPE[0] ? (kpe + (size_t)(t) * 2048 + kLoc[0])                  \
                               : (KpH + (size_t)(t) * 4096 + kLoc[0]);                 \
        gload_lds16(_s, _k + kO[0]); }                                                 \
      if (tid < 256){                                                                  \
        const u16* _s = kPE[1] ? (kpe + (size_t)(t) * 2048 + kLoc[1])                  \
                               : (KpH + (size_t)(t) * 4096 + kLoc[1]);                 \
        gload_lds16(_s, _k + kO[1]); }                                                 \
      gload_lds16(VtH + vSrc + (t) * 32, _v + vO);                                     \
    } while (0)

  const int nt = 4 * qt + 4;

  bf16x8 qf[6];
  const u16* Qbase = Qp + (size_t)(h * T_SEQ + qbase + lm) * 192 + lg * 8;
  #pragma unroll
  for (int dk = 0; dk < 6; dk++) qf[dk] = *(const bf16x8*)(Qbase + dk * 32);

  f32x4 o_[8] = {};
  float m_[4], l_[4];
  #pragma unroll
  for (int q = 0; q < 4; q++){ m_[q] = -3.0e38f; l_[q] = 0.f; }

  STAGE_KV(0, 0);

  #pragma unroll 1
  for (int kt = 0; kt < nt; kt++){
    const int t0 = kt * 32;
    const int bsel = kt & 1;
    asm volatile("s_waitcnt vmcnt(0)" ::: "memory");
    __builtin_amdgcn_sched_barrier(0);
    __builtin_amdgcn_s_barrier();
    if (kt + 1 < nt) STAGE_KV(kt + 1, bsel ^ 1);
    const char* Kb = lds + bsel * 12288;
    const char* Vb = lds + 24576 + bsel * 8192;

    f32x4 s_[2] = {};
    __builtin_amdgcn_s_setprio(1);
    #pragma unroll
    for (int hh = 0; hh < 2; hh++){
      const int r = hh * 16 + lm;
      const int rb = r * 384, rx = r & 7;
      #pragma unroll
      for (int dk = 0; dk < 6; dk++){
        bf16x8 kf = *(const bf16x8*)(Kb + rb + (((dk * 4 + lg) ^ rx) << 4));
        s_[hh] = __builtin_amdgcn_mfma_f32_16x16x32_bf16(qf[dk], kf, s_[hh], 0, 0, 0);
      }
    }
    __builtin_amdgcn_s_setprio(0);
    if (kt + 4 >= nt){
      #pragma unroll
      for (int hh = 0; hh < 2; hh++)
        #pragma unroll
        for (int q = 0; q < 4; q++){
          int col = t0 + hh * 16 + lm;
          int qrow = qbase + lg * 4 + q;
          if (col > qrow) s_[hh][q] = -3.0e38f;
        }
    }
    float pm[4];
    #pragma unroll
    for (int q = 0; q < 4; q++) pm[q] = fmaxf(s_[0][q], s_[1][q]);
    int ok = (pm[0] <= m_[0] + 8.f) & (pm[1] <= m_[1] + 8.f) &
             (pm[2] <= m_[2] + 8.f) & (pm[3] <= m_[3] + 8.f);
    if (!__all(ok)){
      #pragma unroll
      for (int q = 0; q < 4; q++){
        float v = pm[q];
        #pragma unroll
        for (int off = 8; off; off >>= 1) v = fmaxf(v, __shfl_xor(v, off));
        float mn = fmaxf(m_[q], v);
        float alpha = (m_[q] <= -1.0e37f) ? 0.f : exp2f(m_[q] - mn);
        l_[q] *= alpha;
        #pragma unroll
        for (int n = 0; n < 8; n++) o_[n][q] *= alpha;
        m_[q] = mn;
      }
    }
    #pragma unroll
    for (int q = 0; q < 4; q++){
      #pragma unroll
      for (int hh = 0; hh < 2; hh++){
        float p = exp2f(s_[hh][q] - m_[q]);
        l_[q] += p;
        ((__bf16*)Pw)[(lg * 4 + q) * 40 + hh * 16 + lm] = (__bf16)p;
      }
    }
    asm volatile("s_waitcnt lgkmcnt(0)" ::: "memory");
    __builtin_amdgcn_sched_barrier(0);
    bf16x8 pf = *(const bf16x8*)((const char*)Pw + lm * 80 + lg * 16);
    __builtin_amdgcn_s_setprio(1);
    #pragma unroll
    for (int n = 0; n < 8; n++){
      const int d = n * 16 + lm;
      bf16x8 vf = *(const bf16x8*)(Vb + d * 64 + ((lg ^ ((d >> 1) & 3)) << 4));
      o_[n] = __builtin_amdgcn_mfma_f32_16x16x32_bf16(pf, vf, o_[n], 0, 0, 0);
    }
    __builtin_amdgcn_s_setprio(0);
  }

  #pragma unroll
  for (int q = 0; q < 4; q++){
    #pragma unroll
    for (int off = 8; off; off >>= 1) l_[q] += __shfl_xor(l_[q], off);
  }
  float inv[4];
  #pragma unroll
  for (int q = 0; q < 4; q++) inv[q] = 1.f / l_[q];
  #pragma unroll
  for (int n = 0; n < 8; n++)
    #pragma unroll
    for (int q = 0; q < 4; q++){
      int r = qbase + lg * 4 + q;
      ((__bf16*)attnb)[(size_t)r * 4096 + h * 128 + n * 16 + lm] = (__bf16)(o_[n][q] * inv[q]);
    }
  #undef STAGE_KV
}

// =====================================================================
extern "C" void kernel_launch(void* const* d_in, const int* in_sizes, int n_in,
                              void* d_out, int out_size, void* d_ws, size_t ws_size,
                              hipStream_t stream){
  const int*   positions = (const int*)d_in[0];
  const float* hidden    = (const float*)d_in[1];
  const float* Wqa       = (const float*)d_in[2];
  const float* q_a_ln    = (const float*)d_in[3];
  const float* Wqb       = (const float*)d_in[4];
  const float* Wkva      = (const float*)d_in[5];
  const float* kv_a_ln   = (const float*)d_in[6];
  const float* Wkvb      = (const float*)d_in[7];
  const float* Wo        = (const float*)d_in[8];
  float* out = (float*)d_out;
  char* ws = (char*)d_ws;

  // workspace layout (bytes); peak ~198 MiB
  const size_t o_hidB  = 0;          // bf16 2048x4096 (dead after comb GEMM; attnb aliases)
  const size_t o_cos   = 16777216;
  const size_t o_sin   = 17039360;
  const size_t o_kpe   = 17301504;   // bf16 2048x64
  const size_t o_comb  = 17563648;   // f32 2048x2176
  const size_t o_qln   = 35389440;   // bf16 2048x1536
  const size_t o_kva   = 41680896;   // bf16 2048x512
  const size_t o_WqaT  = 43778048;   // bf16 1536x4096
  const size_t o_WkvaT = 56360960;   // bf16 640x4096 (adjacent to WqaT)
  const size_t o_WqbT  = 61603840;   // bf16 6144x1536
  const size_t o_WkvbT = 80478208;   // bf16 8192x512
  const size_t o_Qp    = 88866816;   // bf16 32x2048x192
  const size_t o_Kp    = 114032640;  // bf16 32x2048x128
  const size_t o_Vt    = 147587072;  // bf16 32x128x2048
  const size_t o_WoT   = 164364288;  // bf16 4096x4096, ends 197918720

  u16*   hidB  = (u16*)(ws + o_hidB);
  u16*   attnb = (u16*)(ws + o_hidB);   // aliases hidB (disjoint lifetimes)
  float* cosT  = (float*)(ws + o_cos);
  float* sinT  = (float*)(ws + o_sin);
  u16*   kpe   = (u16*)(ws + o_kpe);
  float* comb  = (float*)(ws + o_comb);
  u16*   qln   = (u16*)(ws + o_qln);
  u16*   kva   = (u16*)(ws + o_kva);
  u16*   WqaT  = (u16*)(ws + o_WqaT);
  u16*   WkvaT = (u16*)(ws + o_WkvaT);
  u16*   WqbT  = (u16*)(ws + o_WqbT);
  u16*   WkvbT = (u16*)(ws + o_WkvbT);
  u16*   Qp    = (u16*)(ws + o_Qp);
  u16*   Kp    = (u16*)(ws + o_Kp);
  u16*   Vt    = (u16*)(ws + o_Vt);
  u16*   WoT   = (u16*)(ws + o_WoT);

  double mscale = 0.1 * log(40.0) + 1.0;
  double scaling_d = pow(192.0, -0.5) * mscale * mscale;
  float scaling_log2 = (float)(scaling_d * 1.4426950408889634);
  const double PI = 3.14159265358979323846;
  double cd_fast = 64.0 * log(4096.0 / (32.0 * 2.0 * PI)) / (2.0 * log(10000.0));
  double cd_slow = 64.0 * log(4096.0 / ( 1.0 * 2.0 * PI)) / (2.0 * log(10000.0));
  double lo_d = fmax(floor(cd_fast), 0.0);
  double hi_d = fmin(ceil(cd_slow), 63.0);
  float lo = (float)lo_d;
  float denom = (float)fmax(hi_d - lo_d, 0.001);

  // 1. transposes + hidden cast + rope table, ONE launch
  pre_batch<<<11904, 256, 0, stream>>>(Wqa, WqaT, Wkva, WkvaT, Wqb, WqbT, Wkvb, WkvbT,
                                       Wo, WoT, hidden, hidB, positions, cosT, sinT, lo, denom);
  // 2. comb = hid @ [Wqa|Wkva]
  gemm_bt<0><<<dim3(2176 / 128, 2048 / 128), 256, 0, stream>>>(
      hidB, WqaT, comb, nullptr, nullptr, nullptr, nullptr, nullptr,
      nullptr, nullptr, 0.f, 2048, 2176, 4096);
  // 3. norms + k_pe rope
  rmsnorm_cast<<<2048, 256, 0, stream>>>(comb, 2176, 1536, q_a_ln, qln, 1536);
  rmsnorm_cast<<<2048, 256, 0, stream>>>(comb + 1536, 2176, 512, kv_a_ln, kva, 512);
  rope_kpe<<<256, 256, 0, stream>>>(comb, 2176, 2048, cosT, sinT, kpe);
  // 4+5 merged: Qp = rope(qln @ Wqb)*scale  ||  Kp+Vt = kva @ Wkvb
  gemm_bt<3><<<1792, 256, 0, stream>>>(
      qln, WqbT, nullptr, Qp, Kp, Vt, kva, WkvbT,
      cosT, sinT, scaling_log2, 0, 0, 0);
  // 6. attention: 512 balanced strips
  flash_attn<<<512, 512, 0, stream>>>(Qp, Kp, kpe, Vt, attnb);
  // 7. out = attn @ Wo
  gemm_bt<0><<<dim3(4096 / 128, 2048 / 128), 256, 0, stream>>>(
      attnb, WoT, out, nullptr, nullptr, nullptr, nullptr, nullptr,
      nullptr, nullptr, 0.f, 2048, 4096, 4096);
}

// Round 16
// 390.217 us; speedup vs baseline: 1.1396x; 1.1396x over previous
//
#include <hip/hip_runtime.h>
#include <math.h>

typedef __bf16 bf16x8 __attribute__((ext_vector_type(8)));
typedef float f32x4 __attribute__((ext_vector_type(4)));
typedef unsigned short u16;
typedef unsigned int u32;

#define T_SEQ 2048
#define NHEAD 32

// float -> bf16 bits, round-nearest-even
__device__ __forceinline__ u16 f2bu(float f){
  u32 u = __float_as_uint(f);
  u32 r = (u + 0x7fffu + ((u >> 16) & 1u)) >> 16;
  return (u16)r;
}

__device__ __forceinline__ void gload_lds16(const void* g, void* l){
  __builtin_amdgcn_global_load_lds((const __attribute__((address_space(1))) u32*)g,
                                   (__attribute__((address_space(3))) u32*)l, 16, 0, 0);
}

// ---------------- elementwise cast f32 -> bf16 (vector4) ----------------
__global__ void cast_f32_bf16(const float* __restrict__ in, u16* __restrict__ out, int n4){
  int i = blockIdx.x * blockDim.x + threadIdx.x;
  int stride = gridDim.x * blockDim.x;
  for (; i < n4; i += stride){
    float4 v = ((const float4*)in)[i];
    ushort4 o;
    o.x = f2bu(v.x); o.y = f2bu(v.y); o.z = f2bu(v.z); o.w = f2bu(v.w);
    ((ushort4*)out)[i] = o;
  }
}

// ---------------- transpose + cast body (vectorized) ----------------
__device__ __forceinline__ void tc_body(const float* __restrict__ src, u16* __restrict__ dst,
                                        int K, int N, int k0, int n0){
  __shared__ float tile[64][65];
  int t = threadIdx.x;
  int rr = t >> 4, c4 = (t & 15) * 4;
  #pragma unroll
  for (int i = 0; i < 4; i++){
    int r = rr + i * 16;
    int n = n0 + c4;
    float4 v;
    if (n < N) v = *(const float4*)(src + (size_t)(k0 + r) * N + n);
    else       v = make_float4(0.f, 0.f, 0.f, 0.f);
    tile[r][c4]     = v.x;
    tile[r][c4 + 1] = v.y;
    tile[r][c4 + 2] = v.z;
    tile[r][c4 + 3] = v.w;
  }
  __syncthreads();
  #pragma unroll
  for (int i = 0; i < 4; i++){
    int n = rr + i * 16;
    ushort4 o;
    o.x = f2bu(tile[c4 + 0][n]);
    o.y = f2bu(tile[c4 + 1][n]);
    o.z = f2bu(tile[c4 + 2][n]);
    o.w = f2bu(tile[c4 + 3][n]);
    *(ushort4*)(dst + (size_t)(n0 + n) * K + k0 + c4) = o;
  }
}

// ---------------- batched transpose: all 5 weights in ONE launch ----------------
__global__ __launch_bounds__(256) void transpose_batch(
    const float* __restrict__ Wqa, u16* __restrict__ WqaT,
    const float* __restrict__ Wkva, u16* __restrict__ WkvaT,
    const float* __restrict__ Wqb, u16* __restrict__ WqbT,
    const float* __restrict__ Wkvb, u16* __restrict__ WkvbT,
    const float* __restrict__ Wo, u16* __restrict__ WoT){
  int bid = blockIdx.x;
  const float* s; u16* d; int K, N, gx, l;
  if (bid < 1536)      { s = Wqa;  d = WqaT;  K = 4096; N = 1536; gx = 64; l = bid; }
  else if (bid < 2176) { s = Wkva; d = WkvaT; K = 4096; N = 576;  gx = 64; l = bid - 1536; }
  else if (bid < 4480) { s = Wqb;  d = WqbT;  K = 1536; N = 6144; gx = 24; l = bid - 2176; }
  else if (bid < 5504) { s = Wkvb; d = WkvbT; K = 512;  N = 8192; gx = 8;  l = bid - 4480; }
  else                 { s = Wo;   d = WoT;   K = 4096; N = 4096; gx = 64; l = bid - 5504; }
  tc_body(s, d, K, N, (l % gx) * 64, (l / gx) * 64);
}

// ---------------- YaRN rope table ----------------
__global__ void rope_table(const int* __restrict__ positions, float* __restrict__ cosT,
                           float* __restrict__ sinT, float lo, float denom){
  int idx = blockIdx.x * blockDim.x + threadIdx.x;
  if (idx >= T_SEQ * 32) return;
  int t = idx >> 5, i = idx & 31;
  float pf = powf(10000.f, (float)i / 32.f);
  float inv_extra = 1.f / pf;
  float inv_inter = 1.f / (40.f * pf);
  float ramp = fminf(fmaxf(((float)i - lo) / denom, 0.f), 1.f);
  float invf = inv_inter * ramp + inv_extra * (1.f - ramp);
  float fr = (float)positions[t] * invf;
  cosT[idx] = cosf(fr);
  sinT[idx] = sinf(fr);
}

// ---------------- rmsnorm (f32 in, bf16 out) ----------------
__global__ void rmsnorm_cast(const float* __restrict__ in, int istride, int n,
                             const float* __restrict__ w, u16* __restrict__ out, int ostride){
  int row = blockIdx.x;
  const float* x = in + (size_t)row * istride;
  float ss = 0.f;
  for (int c = threadIdx.x; c < n; c += blockDim.x){ float v = x[c]; ss += v * v; }
  #pragma unroll
  for (int off = 1; off < 64; off <<= 1) ss += __shfl_xor(ss, off);
  __shared__ float wsum[4];
  if ((threadIdx.x & 63) == 0) wsum[threadIdx.x >> 6] = ss;
  __syncthreads();
  float tot = wsum[0] + wsum[1] + wsum[2] + wsum[3];
  float scale = rsqrtf(tot / (float)n + 1e-6f);
  for (int c = threadIdx.x; c < n; c += blockDim.x)
    out[(size_t)row * ostride + c] = f2bu(x[c] * scale * w[c]);
}

// ---------------- rope on k_pe ----------------
__global__ void rope_kpe(const float* __restrict__ lat, int lstride, int loff,
                         const float* __restrict__ cosT,
                         const float* __restrict__ sinT, u16* __restrict__ kpe){
  int idx = blockIdx.x * blockDim.x + threadIdx.x;
  if (idx >= T_SEQ * 32) return;
  int t = idx >> 5, i = idx & 31;
  float x1 = lat[(size_t)t * lstride + loff + 2 * i];
  float x2 = lat[(size_t)t * lstride + loff + 2 * i + 1];
  float c = cosT[idx], s = sinT[idx];
  kpe[t * 64 + 2 * i]     = f2bu(x1 * c - x2 * s);
  kpe[t * 64 + 2 * i + 1] = f2bu(x2 * c + x1 * s);
}

// ---------------- GEMM (round-4 structure) ----------------
template<int EPI>
__global__ __launch_bounds__(256) void gemm_bt(const u16* __restrict__ A, const u16* __restrict__ BT,
                                               float* __restrict__ C, u16* __restrict__ O1,
                                               u16* __restrict__ O2,
                                               const float* __restrict__ cosT,
                                               const float* __restrict__ sinT,
                                               float scaling, int M, int N, int K){
  __shared__ __align__(1024) char lds[32768];
  const int tid = threadIdx.x;
  const int wave = tid >> 6, lane = tid & 63;
  const int lg = lane >> 4, lm = lane & 15;

  int gx = gridDim.x;
  int nwg = gx * gridDim.y;
  int orig = blockIdx.y * gx + blockIdx.x;
  int qq = nwg >> 3, rr_ = nwg & 7, xc = orig & 7, rest = orig >> 3;
  int wg = (xc < rr_ ? xc * (qq + 1) : rr_ * (qq + 1) + (xc - rr_) * qq) + rest;
  const int bn = (wg % gx) * 128, bm = (wg / gx) * 128;

  const int wr = (wave >> 1) * 64, wc = (wave & 1) * 64;
  f32x4 acc[4][4] = {};
  int srow[2], scol[2], soff[2];
  #pragma unroll
  for (int j = 0; j < 2; j++){
    int o = (wave * 2 + j) * 1024 + lane * 16;
    int row = o >> 6;
    int cg = ((o >> 4) & 3) ^ ((row >> 1) & 3);
    srow[j] = row; scol[j] = cg * 8; soff[j] = (wave * 2 + j) * 1024;
  }

  #pragma unroll
  for (int j = 0; j < 2; j++){
    gload_lds16(A  + (size_t)(bm + srow[j]) * K + scol[j], lds + soff[j]);
    gload_lds16(BT + (size_t)(bn + srow[j]) * K + scol[j], lds + 16384 + soff[j]);
  }

  int cur = 0;
  for (int k0 = 0; k0 < K; k0 += 32){
    if (k0 + 32 < K){
      char* dA = lds + (cur ^ 1) * 8192;
      char* dB = lds + 16384 + (cur ^ 1) * 8192;
      #pragma unroll
      for (int j = 0; j < 2; j++){
        gload_lds16(A  + (size_t)(bm + srow[j]) * K + k0 + 32 + scol[j], dA + soff[j]);
        gload_lds16(BT + (size_t)(bn + srow[j]) * K + k0 + 32 + scol[j], dB + soff[j]);
      }
      asm volatile("s_waitcnt vmcnt(4)" ::: "memory");
    } else {
      asm volatile("s_waitcnt vmcnt(0)" ::: "memory");
    }
    __builtin_amdgcn_sched_barrier(0);
    __builtin_amdgcn_s_barrier();

    const char* ldsA = lds + cur * 8192;
    const char* ldsB = lds + 16384 + cur * 8192;
    bf16x8 af[4], bfr[4];
    #pragma unroll
    for (int m = 0; m < 4; m++){
      int r = wr + m * 16 + lm;
      af[m] = *(const bf16x8*)(ldsA + r * 64 + ((lg ^ ((r >> 1) & 3)) << 4));
    }
    #pragma unroll
    for (int n = 0; n < 4; n++){
      int r = wc + n * 16 + lm;
      bfr[n] = *(const bf16x8*)(ldsB + r * 64 + ((lg ^ ((r >> 1) & 3)) << 4));
    }
    __builtin_amdgcn_s_setprio(1);
    #pragma unroll
    for (int m = 0; m < 4; m++)
      #pragma unroll
      for (int n = 0; n < 4; n++)
        acc[m][n] = __builtin_amdgcn_mfma_f32_16x16x32_bf16(af[m], bfr[n], acc[m][n], 0, 0, 0);
    __builtin_amdgcn_s_setprio(0);
    __builtin_amdgcn_s_barrier();
    cur ^= 1;
  }

  #pragma unroll
  for (int m = 0; m < 4; m++)
    #pragma unroll
    for (int n = 0; n < 4; n++){
      const int r0 = bm + wr + m * 16 + lg * 4;
      const int c  = bn + wc + n * 16 + lm;
      if (EPI == 0){
        #pragma unroll
        for (int q = 0; q < 4; q++)
          C[(size_t)(r0 + q) * N + c] = acc[m][n][q];
      } else if (EPI == 1){
        #pragma unroll
        for (int q = 0; q < 4; q++){
          float v = acc[m][n][q];
          float vp = __shfl_xor(v, 1);
          int h = c / 192, d = c - h * 192;
          float outv;
          if (d < 128) outv = v;
          else {
            int i = (d - 128) >> 1;
            float co = cosT[(r0 + q) * 32 + i], si = sinT[(r0 + q) * 32 + i];
            outv = (d & 1) ? (v * co + vp * si) : (v * co - vp * si);
          }
          O1[(size_t)h * T_SEQ * 192 + (size_t)(r0 + q) * 192 + d] = f2bu(outv * scaling);
        }
      } else {
        int h = c >> 8, d = c & 255;
        if (d < 128){
          #pragma unroll
          for (int q = 0; q < 4; q++)
            O1[(size_t)h * T_SEQ * 128 + (size_t)(r0 + q) * 128 + d] = f2bu(acc[m][n][q]);
        } else {
          ushort4 o;
          o.x = f2bu(acc[m][n][0]); o.y = f2bu(acc[m][n][1]);
          o.z = f2bu(acc[m][n][2]); o.w = f2bu(acc[m][n][3]);
          *(ushort4*)(O2 + (size_t)(h * 128 + (d - 128)) * T_SEQ + r0) = o;
        }
      }
    }
}

// ---------------- flash attention v12: r12 structure + VALU cuts ----------------
// 8 waves (512 thr), QBLK=128 (16 q/wave), KVBLK=32, double-buffered K/V (50KB LDS),
// single barrier/iter, exp2-domain softmax, defer-max, balanced strips, XCD affinity.
__global__ __launch_bounds__(512, 4) void flash_attn(const u16* __restrict__ Qp, const u16* __restrict__ Kp,
                                                     const u16* __restrict__ kpe, const u16* __restrict__ Vt,
                                                     u16* __restrict__ attnb){
  const int b = blockIdx.x;
  const int h = (b & 7) + 8 * ((b >> 3) & 3);
  const int qt = (b < 256) ? (15 - (b >> 5)) : ((b - 256) >> 5);
  const int tid = threadIdx.x;
  const int wave = tid >> 6, lane = tid & 63;
  const int lg = lane >> 4, lm = lane & 15;
  const int qbase = qt * 128 + wave * 16;

  __shared__ __align__(1024) char lds[51200];
  u16* Pw = (u16*)(lds + 40960 + wave * 1280);   // [16][40] u16

  const u16* KpH = Kp + (size_t)h * T_SEQ * 128;
  const u16* VtH = Vt + (size_t)h * 128 * T_SEQ;

  int kO[2], kLoc[2], kPE[2];
  #pragma unroll
  for (int j = 0; j < 2; j++){
    int o = tid + 512 * j;                     // j=1 only used by tid<256
    int r = (o / 24) & 31, c = o % 24;
    int cx = c ^ (r & 7);
    kO[j] = o * 16;
    if (cx < 16){ kPE[j] = 0; kLoc[j] = r * 128 + cx * 8; }
    else        { kPE[j] = 1; kLoc[j] = r * 64 + (cx - 16) * 8; }
  }
  int vO, vSrc;
  { int o = tid; int d = o >> 2, c = o & 3; vO = o * 16; vSrc = d * T_SEQ + ((c ^ ((d >> 1) & 3)) << 3); }

  #define STAGE_KV(t, bi)                                                              \
    do {                                                                               \
      char* _k = lds + (bi) * 12288;                                                   \
      char* _v = lds + 24576 + (bi) * 8192;                                            \
      { const u16* _s = kPE[0] ? (kpe + (size_t)(t) * 2048 + kLoc[0])                  \
                               : (KpH + (size_t)(t) * 4096 + kLoc[0]);                 \
        gload_lds16(_s, _k + kO[0]); }                                                 \
      if (tid < 256){                                                                  \
        const u16* _s = kPE[1] ? (kpe + (size_t)(t) * 2048 + kLoc[1])                  \
                               : (KpH + (size_t)(t) * 4096 + kLoc[1]);                 \
        gload_lds16(_s, _k + kO[1]); }                                                 \
      gload_lds16(VtH + vSrc + (t) * 32, _v + vO);                                     \
    } while (0)

  const int nt = 4 * qt + 4;

  bf16x8 qf[6];
  const u16* Qbase = Qp + (size_t)(h * T_SEQ + qbase + lm) * 192 + lg * 8;
  #pragma unroll
  for (int dk = 0; dk < 6; dk++) qf[dk] = *(const bf16x8*)(Qbase + dk * 32);

  f32x4 o_[8] = {};
  float m_[4], l_[4];
  #pragma unroll
  for (int q = 0; q < 4; q++){ m_[q] = -3.0e38f; l_[q] = 0.f; }

  STAGE_KV(0, 0);

  #pragma unroll 1
  for (int kt = 0; kt < nt; kt++){
    const int t0 = kt * 32;
    const int bsel = kt & 1;
    asm volatile("s_waitcnt vmcnt(0)" ::: "memory");
    __builtin_amdgcn_sched_barrier(0);
    __builtin_amdgcn_s_barrier();
    if (kt + 1 < nt) STAGE_KV(kt + 1, bsel ^ 1);
    const char* Kb = lds + bsel * 12288;
    const char* Vb = lds + 24576 + bsel * 8192;

    f32x4 s_[2] = {};
    __builtin_amdgcn_s_setprio(1);
    #pragma unroll
    for (int hh = 0; hh < 2; hh++){
      const int r = hh * 16 + lm;
      const int rb = r * 384, rx = r & 7;
      #pragma unroll
      for (int dk = 0; dk < 6; dk++){
        bf16x8 kf = *(const bf16x8*)(Kb + rb + (((dk * 4 + lg) ^ rx) << 4));
        s_[hh] = __builtin_amdgcn_mfma_f32_16x16x32_bf16(qf[dk], kf, s_[hh], 0, 0, 0);
      }
    }
    __builtin_amdgcn_s_setprio(0);
    if (kt + 4 >= nt){
      #pragma unroll
      for (int hh = 0; hh < 2; hh++)
        #pragma unroll
        for (int q = 0; q < 4; q++){
          int col = t0 + hh * 16 + lm;
          int qrow = qbase + lg * 4 + q;
          if (col > qrow) s_[hh][q] = -3.0e38f;
        }
    }
    float pm[4];
    #pragma unroll
    for (int q = 0; q < 4; q++) pm[q] = fmaxf(s_[0][q], s_[1][q]);
    int ok = (pm[0] <= m_[0] + 8.f) & (pm[1] <= m_[1] + 8.f) &
             (pm[2] <= m_[2] + 8.f) & (pm[3] <= m_[3] + 8.f);
    if (!__all(ok)){
      #pragma unroll
      for (int q = 0; q < 4; q++){
        float v = pm[q];
        #pragma unroll
        for (int off = 8; off; off >>= 1) v = fmaxf(v, __shfl_xor(v, off));
        float mn = fmaxf(m_[q], v);
        float alpha = (m_[q] <= -1.0e37f) ? 0.f : exp2f(m_[q] - mn);
        l_[q] *= alpha;
        #pragma unroll
        for (int n = 0; n < 8; n++) o_[n][q] *= alpha;
        m_[q] = mn;
      }
    }
    #pragma unroll
    for (int q = 0; q < 4; q++){
      #pragma unroll
      for (int hh = 0; hh < 2; hh++){
        float p = exp2f(s_[hh][q] - m_[q]);
        l_[q] += p;
        ((__bf16*)Pw)[(lg * 4 + q) * 40 + hh * 16 + lm] = (__bf16)p;
      }
    }
    asm volatile("s_waitcnt lgkmcnt(0)" ::: "memory");
    __builtin_amdgcn_sched_barrier(0);
    bf16x8 pf = *(const bf16x8*)((const char*)Pw + lm * 80 + lg * 16);
    __builtin_amdgcn_s_setprio(1);
    #pragma unroll
    for (int n = 0; n < 8; n++){
      const int d = n * 16 + lm;
      bf16x8 vf = *(const bf16x8*)(Vb + d * 64 + ((lg ^ ((d >> 1) & 3)) << 4));
      o_[n] = __builtin_amdgcn_mfma_f32_16x16x32_bf16(pf, vf, o_[n], 0, 0, 0);
    }
    __builtin_amdgcn_s_setprio(0);
  }

  #pragma unroll
  for (int q = 0; q < 4; q++){
    #pragma unroll
    for (int off = 8; off; off >>= 1) l_[q] += __shfl_xor(l_[q], off);
  }
  float inv[4];
  #pragma unroll
  for (int q = 0; q < 4; q++) inv[q] = 1.f / l_[q];
  #pragma unroll
  for (int n = 0; n < 8; n++)
    #pragma unroll
    for (int q = 0; q < 4; q++){
      int r = qbase + lg * 4 + q;
      ((__bf16*)attnb)[(size_t)r * 4096 + h * 128 + n * 16 + lm] = (__bf16)(o_[n][q] * inv[q]);
    }
  #undef STAGE_KV
}

// =====================================================================
extern "C" void kernel_launch(void* const* d_in, const int* in_sizes, int n_in,
                              void* d_out, int out_size, void* d_ws, size_t ws_size,
                              hipStream_t stream){
  const int*   positions = (const int*)d_in[0];
  const float* hidden    = (const float*)d_in[1];
  const float* Wqa       = (const float*)d_in[2];
  const float* q_a_ln    = (const float*)d_in[3];
  const float* Wqb       = (const float*)d_in[4];
  const float* Wkva      = (const float*)d_in[5];
  const float* kv_a_ln   = (const float*)d_in[6];
  const float* Wkvb      = (const float*)d_in[7];
  const float* Wo        = (const float*)d_in[8];
  float* out = (float*)d_out;
  char* ws = (char*)d_ws;

  // workspace layout (bytes); peak ~198 MiB
  const size_t o_hidB  = 0;          // bf16 2048x4096 (dead after comb GEMM; attnb aliases)
  const size_t o_cos   = 16777216;
  const size_t o_sin   = 17039360;
  const size_t o_kpe   = 17301504;   // bf16 2048x64
  const size_t o_comb  = 17563648;   // f32 2048x2176
  const size_t o_qln   = 35389440;   // bf16 2048x1536
  const size_t o_kva   = 41680896;   // bf16 2048x512
  const size_t o_WqaT  = 43778048;   // bf16 1536x4096
  const size_t o_WkvaT = 56360960;   // bf16 640x4096 (adjacent to WqaT)
  const size_t o_WqbT  = 61603840;   // bf16 6144x1536
  const size_t o_WkvbT = 80478208;   // bf16 8192x512
  const size_t o_Qp    = 88866816;   // bf16 32x2048x192
  const size_t o_Kp    = 114032640;  // bf16 32x2048x128
  const size_t o_Vt    = 147587072;  // bf16 32x128x2048
  const size_t o_WoT   = 164364288;  // bf16 4096x4096, ends 197918720

  u16*   hidB  = (u16*)(ws + o_hidB);
  u16*   attnb = (u16*)(ws + o_hidB);   // aliases hidB (disjoint lifetimes)
  float* cosT  = (float*)(ws + o_cos);
  float* sinT  = (float*)(ws + o_sin);
  u16*   kpe   = (u16*)(ws + o_kpe);
  float* comb  = (float*)(ws + o_comb);
  u16*   qln   = (u16*)(ws + o_qln);
  u16*   kva   = (u16*)(ws + o_kva);
  u16*   WqaT  = (u16*)(ws + o_WqaT);
  u16*   WkvaT = (u16*)(ws + o_WkvaT);
  u16*   WqbT  = (u16*)(ws + o_WqbT);
  u16*   WkvbT = (u16*)(ws + o_WkvbT);
  u16*   Qp    = (u16*)(ws + o_Qp);
  u16*   Kp    = (u16*)(ws + o_Kp);
  u16*   Vt    = (u16*)(ws + o_Vt);
  u16*   WoT   = (u16*)(ws + o_WoT);

  double mscale = 0.1 * log(40.0) + 1.0;
  double scaling_d = pow(192.0, -0.5) * mscale * mscale;
  float scaling_log2 = (float)(scaling_d * 1.4426950408889634);
  const double PI = 3.14159265358979323846;
  double cd_fast = 64.0 * log(4096.0 / (32.0 * 2.0 * PI)) / (2.0 * log(10000.0));
  double cd_slow = 64.0 * log(4096.0 / ( 1.0 * 2.0 * PI)) / (2.0 * log(10000.0));
  double lo_d = fmax(floor(cd_fast), 0.0);
  double hi_d = fmin(ceil(cd_slow), 63.0);
  float lo = (float)lo_d;
  float denom = (float)fmax(hi_d - lo_d, 0.001);

  // 1. ALL weight transposes in one launch; cast hidden; rope table
  transpose_batch<<<9600, 256, 0, stream>>>(Wqa, WqaT, Wkva, WkvaT, Wqb, WqbT,
                                            Wkvb, WkvbT, Wo, WoT);
  cast_f32_bf16<<<2048, 256, 0, stream>>>(hidden, hidB, T_SEQ * 4096 / 4);
  rope_table<<<256, 256, 0, stream>>>(positions, cosT, sinT, lo, denom);
  // 2. comb = hid @ [Wqa|Wkva]
  gemm_bt<0><<<dim3(2176 / 128, 2048 / 128), 256, 0, stream>>>(hidB, WqaT, comb, nullptr, nullptr,
                                                               nullptr, nullptr, 0.f, 2048, 2176, 4096);
  // 3. norms + k_pe rope
  rmsnorm_cast<<<2048, 256, 0, stream>>>(comb, 2176, 1536, q_a_ln, qln, 1536);
  rmsnorm_cast<<<2048, 256, 0, stream>>>(comb + 1536, 2176, 512, kv_a_ln, kva, 512);
  rope_kpe<<<256, 256, 0, stream>>>(comb, 2176, 2048, cosT, sinT, kpe);
  // 4. Qp = rope(qln @ Wqb) * scaling*log2e, fused epilogue
  gemm_bt<1><<<dim3(6144 / 128, 2048 / 128), 256, 0, stream>>>(qln, WqbT, nullptr, Qp, nullptr,
                                                               cosT, sinT, scaling_log2, 2048, 6144, 1536);
  // 5. Kp(128-stride) + Vt(direct transposed) = kva @ Wkvb, fused epilogue
  gemm_bt<2><<<dim3(8192 / 128, 2048 / 128), 256, 0, stream>>>(kva, WkvbT, nullptr, Kp, Vt,
                                                               nullptr, nullptr, 0.f, 2048, 8192, 512);
  // 6. attention: 512 balanced strips
  flash_attn<<<512, 512, 0, stream>>>(Qp, Kp, kpe, Vt, attnb);
  // 7. out = attn @ Wo
  gemm_bt<0><<<dim3(4096 / 128, 2048 / 128), 256, 0, stream>>>(attnb, WoT, out, nullptr, nullptr,
                                                               nullptr, nullptr, 0.f, 2048, 4096, 4096);
}